// Round 1
// baseline (7746.430 us; speedup 1.0000x reference)
//
#include <hip/hip_runtime.h>
#include <stdint.h>

typedef unsigned short u16;
typedef unsigned int   u32;
typedef __attribute__((ext_vector_type(8))) short short8;
typedef __attribute__((ext_vector_type(4))) float f32x4;

#define AS1 __attribute__((address_space(1)))
#define AS3 __attribute__((address_space(3)))

__device__ __forceinline__ float bf2f(u16 u) {
  union { u32 i; float f; } v; v.i = ((u32)u) << 16; return v.f;
}
__device__ __forceinline__ u16 f2bf(float f) {
  union { float f; u32 i; } v; v.f = f;
  u32 i = v.i;
  i += 0x7FFFu + ((i >> 16) & 1u);   // round-to-nearest-even
  return (u16)(i >> 16);
}

__device__ __forceinline__ void gload16(const u16* src, u16* ldsDst) {
  // 16B per lane, dest = wave-uniform base + lane*16
  __builtin_amdgcn_global_load_lds((const AS1 u32*)src, (AS3 u32*)ldsDst, 16, 0, 0);
}

// ---------------- init: pad+cast x, zero h buffers & counters ----------------
__global__ void k_init(const float* __restrict__ x, u16* __restrict__ xp,
                       float* __restrict__ hbF, u16* __restrict__ hbB,
                       u32* __restrict__ cnt) {
  const long NXP = 32L * 576 * 512;
  long i0 = (long)blockIdx.x * 256 + threadIdx.x;
  for (long i = i0; i < NXP; i += (long)gridDim.x * 256) {
    long b = i / (576 * 512);
    int rem = (int)(i - b * (576 * 512));
    int rr = rem >> 9, dd = rem & 511;
    int t = rr - 31;                       // SAME pad: 31 left, 33 right (incl round-up)
    float v = (t >= 0 && t < 512) ? x[(b * 512 + t) * 512 + dd] : 0.f;
    xp[i] = f2bf(v);
  }
  if (i0 < 32768) { hbF[i0] = 0.f; hbB[i0] = 0; }  // both h parities zeroed
  if (i0 < 512)   cnt[i0] = 0u;
}

// ---------------- transpose + cast fp32 -> bf16 : out[c][r] = in[r][c] -------
__global__ void k_transpose_cast(const float* __restrict__ in, u16* __restrict__ out,
                                 int rows, int cols, long inWStride, long outWStride) {
  __shared__ float tile[64][65];
  const int w = blockIdx.z;
  const float* ip = in + (long)w * inWStride;
  u16* op = out + (long)w * outWStride;
  const int r0 = blockIdx.y * 64, c0 = blockIdx.x * 64;
  const int tr = threadIdx.x >> 6, tc = threadIdx.x & 63;
  #pragma unroll
  for (int p = 0; p < 16; ++p) {
    int rr = p * 4 + tr;
    tile[rr][tc] = ip[(long)(r0 + rr) * cols + c0 + tc];
  }
  __syncthreads();
  #pragma unroll
  for (int p = 0; p < 16; ++p) {
    int rr = p * 4 + tr;
    op[(long)(c0 + rr) * rows + r0 + tc] = f2bf(tile[tc][rr]);
  }
}

// ---------------- tiled MFMA GEMM (conv via w-shift, and XM) -----------------
// A = xp [32][576][512] bf16. B = [w][n][512] bf16 (k-contiguous, i.e. B^T tiles).
// outMode 0: C=za  [b][t][512] bf16 with tanh.  outMode 1: C=XM [t][b][1536] bf16.
__global__ __launch_bounds__(256) void k_gemm(
    const u16* __restrict__ A, const u16* __restrict__ Bm, u16* __restrict__ C,
    int nTiles, int kw, int woff, long bWStride, int outMode)
{
  __shared__ __align__(16) u16 Alds[128 * 64];
  __shared__ __align__(16) u16 Blds[128 * 64];
  const int bid = blockIdx.x;
  const int mt = bid / nTiles, nt = bid - mt * nTiles;
  const int bb = (mt * 128) >> 9;        // batch
  const int t0 = (mt * 128) & 511;       // time tile start
  const int h0 = nt * 128;
  const int tid = threadIdx.x;
  const int wv = tid >> 6, l = tid & 63;
  const int wr = wv >> 1, wc = wv & 1;
  const int sRow = wv * 8 + (l >> 3);
  const int sCol = (l & 7) * 8;
  f32x4 acc[4][4];
  #pragma unroll
  for (int m = 0; m < 4; ++m)
    #pragma unroll
    for (int n = 0; n < 4; ++n) acc[m][n] = f32x4{0.f, 0.f, 0.f, 0.f};

  const int kIters = kw * 8;
  const long aRow0 = (long)(bb * 576 + t0 + woff);
  for (int q = 0; q < kIters; ++q) {
    const int w = q >> 3, dsub = (q & 7) << 6;
    const u16* aB = A + (aRow0 + w) * 512 + dsub + sCol;
    const u16* bB = Bm + (long)w * bWStride + (long)h0 * 512 + dsub + sCol;
    __syncthreads();                      // protect LDS from previous iter readers
    #pragma unroll
    for (int c = 0; c < 4; ++c) {
      gload16(aB + (long)(c * 32 + sRow) * 512, &Alds[c * 2048 + wv * 512]);
      gload16(bB + (long)(c * 32 + sRow) * 512, &Blds[c * 2048 + wv * 512]);
    }
    __syncthreads();
    #pragma unroll
    for (int kk = 0; kk < 2; ++kk) {
      short8 af[4], bf[4];
      #pragma unroll
      for (int m = 0; m < 4; ++m)
        af[m] = *(const short8*)&Alds[(wr * 64 + m * 16 + (l & 15)) * 64 + kk * 32 + (l >> 4) * 8];
      #pragma unroll
      for (int n = 0; n < 4; ++n)
        bf[n] = *(const short8*)&Blds[(wc * 64 + n * 16 + (l & 15)) * 64 + kk * 32 + (l >> 4) * 8];
      #pragma unroll
      for (int m = 0; m < 4; ++m)
        #pragma unroll
        for (int n = 0; n < 4; ++n)
          acc[m][n] = __builtin_amdgcn_mfma_f32_16x16x32_bf16(af[m], bf[n], acc[m][n], 0, 0, 0);
    }
  }
  const int lr = (l >> 4) * 4, lc = l & 15;
  #pragma unroll
  for (int m = 0; m < 4; ++m)
    #pragma unroll
    for (int n = 0; n < 4; ++n)
      #pragma unroll
      for (int r = 0; r < 4; ++r) {
        const int row = mt * 128 + wr * 64 + m * 16 + lr + r;
        const int col = h0 + wc * 64 + n * 16 + lc;
        const float v = acc[m][n][r];
        if (outMode == 0) {
          C[(long)row * 512 + col] = f2bf(tanhf(v));
        } else {
          const int b = row >> 9, t = row & 511;
          C[((long)t * 32 + b) * 1536 + col] = f2bf(v);
        }
      }
}

// ---------------- dza[t][b] = za(b,t,:)·wd2 + (g1-g0) -----------------------
__global__ void k_dza(const u16* __restrict__ za, const float* __restrict__ fskip,
                      const float* __restrict__ ug, float* __restrict__ dza) {
  __shared__ float wd2[512];
  const int t = blockIdx.x, tid = threadIdx.x;
  for (int i = tid; i < 512; i += 256) wd2[i] = fskip[(512 + i) * 2 + 1] - fskip[(512 + i) * 2];
  __syncthreads();
  const int b = tid >> 3, seg = (tid & 7) * 64;
  const u16* row = za + ((long)b * 512 + t) * 512 + seg;
  float pp = 0.f;
  #pragma unroll
  for (int j = 0; j < 8; ++j) {
    short8 v = *(const short8*)&row[j * 8];
    #pragma unroll
    for (int e = 0; e < 8; ++e) pp += bf2f((u16)v[e]) * wd2[seg + j * 8 + e];
  }
  pp += __shfl_xor(pp, 1); pp += __shfl_xor(pp, 2); pp += __shfl_xor(pp, 4);
  if ((tid & 7) == 0) {
    float u0 = ug[((long)t * 32 + b) * 2 + 0], u1 = ug[((long)t * 32 + b) * 2 + 1];
    float g0 = -logf(-logf(u0 + 1e-20f) + 1e-20f);
    float g1 = -logf(-logf(u1 + 1e-20f) + 1e-20f);
    dza[t * 32 + b] = pp + (g1 - g0);
  }
}

// ---------------- persistent recurrence: 8 domains x 8 slices ---------------
// Domain d owns batches 4d..4d+3. Slice s owns h-cols [64s,64s+64); W_rec cols
// {j,512+j,1024+j} register-resident as MFMA B-frags. Per step: exchange h via
// global (fp32 + bf16), device-scope counter barrier per domain.
__global__ __launch_bounds__(256, 1) void k_rnn(
    const u16* __restrict__ XM, const float* __restrict__ dza,
    const float* __restrict__ Wrec, const float* __restrict__ gbias,
    const float* __restrict__ fskip, float* hbF, u16* hbB,
    u32* cnt, float* __restrict__ out)
{
  const int bid = blockIdx.x, d = bid & 7, s = bid >> 3;
  const int tid = threadIdx.x, wv = tid >> 6, l = tid & 63;
  __shared__ __align__(16) float hF[2048];
  __shared__ __align__(16) u16   hBl[2048];
  __shared__ float wd[512];
  __shared__ float s1s[4];
  for (int i = tid; i < 512; i += 256) wd[i] = fskip[i * 2 + 1] - fskip[i * 2];

  const int colb = s * 64 + wv * 16 + (l & 15);
  // load W_rec slice into registers as B-frags (bf16)
  short8 wf[3][16];
  #pragma unroll
  for (int g = 0; g < 3; ++g)
    #pragma unroll
    for (int kk = 0; kk < 16; ++kk) {
      short8 tmp;
      #pragma unroll
      for (int e = 0; e < 8; ++e)
        tmp[e] = (short)f2bf(Wrec[(long)(kk * 32 + (l >> 4) * 8 + e) * 1536 + g * 512 + colb]);
      wf[g][kk] = tmp;
    }
  float bi[3], br[3];
  #pragma unroll
  for (int g = 0; g < 3; ++g) {
    bi[g] = gbias[g * 512 + colb];
    br[g] = gbias[1536 + g * 512 + colb];
  }
  const int myb = d * 4;
  u32* myCnt = cnt + d * 64;

  for (int t = 0; t < 512; ++t) {
    const int p = t & 1;
    // prefetch xm (independent of h) so it lands during the spin
    u16 xmv[3][4];
    if (l < 16) {
      const u16* xr = XM + ((long)t * 32 + myb) * 1536;
      #pragma unroll
      for (int r = 0; r < 4; ++r)
        #pragma unroll
        for (int g = 0; g < 3; ++g)
          xmv[g][r] = xr[(long)r * 1536 + g * 512 + colb];
    }
    const float dzv = dza[t * 32 + myb + wv];

    if (t > 0) {
      if (tid == 0) {
        while (__hip_atomic_load(myCnt, __ATOMIC_ACQUIRE, __HIP_MEMORY_SCOPE_AGENT) < (u32)(8 * t))
          __builtin_amdgcn_s_sleep(1);
      }
      __syncthreads();
      __threadfence();  // invalidate caches before reading peers' h
    }
    // stage h (fp32 + bf16) into LDS
    {
      const long gb = ((long)p * 32 + myb) * 512 + tid * 8;
      f32x4 x0 = *(const f32x4*)&hbF[gb];
      f32x4 x1 = *(const f32x4*)&hbF[gb + 4];
      short8 h8 = *(const short8*)&hbB[gb];
      *(f32x4*)&hF[tid * 8] = x0;
      *(f32x4*)&hF[tid * 8 + 4] = x1;
      *(short8*)&hBl[tid * 8] = h8;
    }
    __syncthreads();
    // skip-gate logit (h part), wave wv handles batch myb+wv
    float pp = 0.f;
    #pragma unroll
    for (int e = 0; e < 8; ++e) pp += hF[wv * 512 + l * 8 + e] * wd[l * 8 + e];
    #pragma unroll
    for (int o = 1; o < 64; o <<= 1) pp += __shfl_xor(pp, o);
    if (l == 0) s1s[wv] = 1.f / (1.f + __expf(-(pp + dzv)));
    __syncthreads();
    // hm = h @ W_rec slice  (M=16 frag, rows 0..3 = batches, rows 4..15 dups)
    f32x4 acc[3];
    acc[0] = f32x4{0.f,0.f,0.f,0.f}; acc[1] = acc[0]; acc[2] = acc[0];
    const int b4 = l & 3;
    #pragma unroll
    for (int kk = 0; kk < 16; ++kk) {
      short8 a = *(const short8*)&hBl[b4 * 512 + kk * 32 + (l >> 4) * 8];
      acc[0] = __builtin_amdgcn_mfma_f32_16x16x32_bf16(a, wf[0][kk], acc[0], 0, 0, 0);
      acc[1] = __builtin_amdgcn_mfma_f32_16x16x32_bf16(a, wf[1][kk], acc[1], 0, 0, 0);
      acc[2] = __builtin_amdgcn_mfma_f32_16x16x32_bf16(a, wf[2][kk], acc[2], 0, 0, 0);
    }
    // gates + skip blend on lanes 0..15 (C rows 0..3 = batches, reg index = batch)
    if (l < 16) {
      #pragma unroll
      for (int r = 0; r < 4; ++r) {
        const float xz = bf2f(xmv[0][r]) + bi[0];
        const float xr_ = bf2f(xmv[1][r]) + bi[1];
        const float xh = bf2f(xmv[2][r]) + bi[2];
        const float hz = acc[0][r] + br[0];
        const float hr = acc[1][r] + br[1];
        const float hh = acc[2][r] + br[2];
        const float z  = 1.f / (1.f + __expf(-(xz + hz)));
        const float rr = 1.f / (1.f + __expf(-(xr_ + hr)));
        const float hc = tanhf(xh + rr * hh);
        const float hp = hF[r * 512 + colb];
        const float ht = z * hp + (1.f - z) * hc;
        const float s1 = s1s[r];
        const float hn = hp + s1 * (ht - hp);
        out[((long)(myb + r) * 512 + t) * 512 + colb] = hn;
        const long go = ((long)(p ^ 1) * 32 + myb + r) * 512 + colb;
        hbF[go] = hn;
        hbB[go] = f2bf(hn);
      }
    }
    __threadfence();           // publish h slices
    __syncthreads();
    if (tid == 0) __hip_atomic_fetch_add(myCnt, 1u, __ATOMIC_RELEASE, __HIP_MEMORY_SCOPE_AGENT);
  }
}

// -----------------------------------------------------------------------------
extern "C" void kernel_launch(void* const* d_in, const int* in_sizes, int n_in,
                              void* d_out, int out_size, void* d_ws, size_t ws_size,
                              hipStream_t stream) {
  (void)in_sizes; (void)n_in; (void)out_size; (void)ws_size;
  const float* x        = (const float*)d_in[0];
  const float* f_after  = (const float*)d_in[1];
  const float* f_skip   = (const float*)d_in[2];
  const float* gru_k    = (const float*)d_in[3];
  const float* gru_rec  = (const float*)d_in[4];
  const float* gru_bias = (const float*)d_in[5];
  const float* ug       = (const float*)d_in[6];
  float* out = (float*)d_out;

  char* ws = (char*)d_ws;
  size_t off = 0;
  auto alloc = [&](size_t bytes) { void* p = ws + off; off = (off + bytes + 255) & ~(size_t)255; return p; };
  u16*  xp   = (u16*)alloc(32L * 576 * 512 * 2);
  u16*  fT   = (u16*)alloc(64L * 512 * 512 * 2);
  u16*  gruT = (u16*)alloc(1536L * 512 * 2);
  u16*  za   = (u16*)alloc(32L * 512 * 512 * 2);
  u16*  XM   = (u16*)alloc(512L * 32 * 1536 * 2);
  float* dza = (float*)alloc(512L * 32 * 4);
  float* hbF = (float*)alloc(2L * 32 * 512 * 4);
  u16*  hbB  = (u16*)alloc(2L * 32 * 512 * 2);
  u32*  cnt  = (u32*)alloc(512 * 4);

  k_init<<<dim3(4096), dim3(256), 0, stream>>>(x, xp, hbF, hbB, cnt);
  // f_after [64][512d][512h] -> fT [64][512h][512d]
  k_transpose_cast<<<dim3(8, 8, 64), dim3(256), 0, stream>>>(f_after, fT, 512, 512, 512L * 512, 512L * 512);
  // gru_kernel [512d][1536h] -> gruT [1536h][512d]
  k_transpose_cast<<<dim3(24, 8, 1), dim3(256), 0, stream>>>(gru_k, gruT, 512, 1536, 0L, 0L);
  // conv: za = tanh(conv1d(x, f_after))
  k_gemm<<<dim3(512), dim3(256), 0, stream>>>(xp, fT, za, 4, 64, 0, 512L * 512, 0);
  // XM = x @ gru_kernel  (stored [t][b][1536])
  k_gemm<<<dim3(1536), dim3(256), 0, stream>>>(xp, gruT, XM, 12, 1, 31, 0L, 1);
  // dza = za·wd2 + gumbel diff
  k_dza<<<dim3(512), dim3(256), 0, stream>>>(za, f_skip, ug, dza);
  // sequential recurrence
  k_rnn<<<dim3(64), dim3(256), 0, stream>>>(XM, dza, gru_rec, gru_bias, f_skip, hbF, hbB, cnt, out);
}

// Round 2
// 2497.159 us; speedup vs baseline: 3.1021x; 3.1021x over previous
//
#include <hip/hip_runtime.h>
#include <stdint.h>

typedef unsigned short u16;
typedef unsigned int   u32;
typedef __attribute__((ext_vector_type(8))) short short8;
typedef __attribute__((ext_vector_type(4))) float f32x4;

#define AS1 __attribute__((address_space(1)))
#define AS3 __attribute__((address_space(3)))

__device__ __forceinline__ float bf2f(u16 u) {
  union { u32 i; float f; } v; v.i = ((u32)u) << 16; return v.f;
}
__device__ __forceinline__ u16 f2bf(float f) {
  union { float f; u32 i; } v; v.f = f;
  u32 i = v.i;
  i += 0x7FFFu + ((i >> 16) & 1u);   // round-to-nearest-even
  return (u16)(i >> 16);
}

__device__ __forceinline__ void gload16(const u16* src, u16* ldsDst) {
  // 16B per lane, dest = wave-uniform base + lane*16
  __builtin_amdgcn_global_load_lds((const AS1 u32*)src, (AS3 u32*)ldsDst, 16, 0, 0);
}

// ---- MALL-coherent (cache-bypassing) accesses for the h exchange -----------
__device__ __forceinline__ f32x4 ldg_sc(const float* p) {
  f32x4 r;
  asm volatile("global_load_dwordx4 %0, %1, off sc0 sc1" : "=v"(r) : "v"(p));
  return r;
}
__device__ __forceinline__ short8 ldg_sc_h(const u16* p) {
  short8 r;
  asm volatile("global_load_dwordx4 %0, %1, off sc0 sc1" : "=v"(r) : "v"(p));
  return r;
}
__device__ __forceinline__ void stg_sc(float* p, float v) {
  asm volatile("global_store_dword %0, %1, off sc0 sc1" :: "v"(p), "v"(v) : "memory");
}
__device__ __forceinline__ void stg_sc_h(u16* p, u16 v) {
  asm volatile("global_store_short %0, %1, off sc0 sc1" :: "v"(p), "v"((u32)v) : "memory");
}

// ---------------- init: pad+cast x, zero h buffers & counters ----------------
__global__ void k_init(const float* __restrict__ x, u16* __restrict__ xp,
                       float* __restrict__ hbF, u16* __restrict__ hbB,
                       u32* __restrict__ cnt) {
  const long NXP = 32L * 576 * 512;
  long i0 = (long)blockIdx.x * 256 + threadIdx.x;
  for (long i = i0; i < NXP; i += (long)gridDim.x * 256) {
    long b = i / (576 * 512);
    int rem = (int)(i - b * (576 * 512));
    int rr = rem >> 9, dd = rem & 511;
    int t = rr - 31;                       // SAME pad: 31 left, 33 right (incl round-up)
    float v = (t >= 0 && t < 512) ? x[(b * 512 + t) * 512 + dd] : 0.f;
    xp[i] = f2bf(v);
  }
  if (i0 < 32768) { hbF[i0] = 0.f; hbB[i0] = 0; }  // both h parities zeroed
  if (i0 < 512)   cnt[i0] = 0u;
}

// ---------------- transpose + cast fp32 -> bf16 : out[c][r] = in[r][c] -------
__global__ void k_transpose_cast(const float* __restrict__ in, u16* __restrict__ out,
                                 int rows, int cols, long inWStride, long outWStride) {
  __shared__ float tile[64][65];
  const int w = blockIdx.z;
  const float* ip = in + (long)w * inWStride;
  u16* op = out + (long)w * outWStride;
  const int r0 = blockIdx.y * 64, c0 = blockIdx.x * 64;
  const int tr = threadIdx.x >> 6, tc = threadIdx.x & 63;
  #pragma unroll
  for (int p = 0; p < 16; ++p) {
    int rr = p * 4 + tr;
    tile[rr][tc] = ip[(long)(r0 + rr) * cols + c0 + tc];
  }
  __syncthreads();
  #pragma unroll
  for (int p = 0; p < 16; ++p) {
    int rr = p * 4 + tr;
    op[(long)(c0 + rr) * rows + r0 + tc] = f2bf(tile[tc][rr]);
  }
}

// ---------------- tiled MFMA GEMM (conv via w-shift, and XM) -----------------
// A = xp [32][576][512] bf16. B = [w][n][512] bf16 (k-contiguous, i.e. B^T tiles).
// outMode 0: C=za  [b][t][512] bf16 with tanh.  outMode 1: C=XM [t][b][1536] bf16.
__global__ __launch_bounds__(256) void k_gemm(
    const u16* __restrict__ A, const u16* __restrict__ Bm, u16* __restrict__ C,
    int nTiles, int kw, int woff, long bWStride, int outMode)
{
  __shared__ __align__(16) u16 Alds[128 * 64];
  __shared__ __align__(16) u16 Blds[128 * 64];
  const int bid = blockIdx.x;
  const int mt = bid / nTiles, nt = bid - mt * nTiles;
  const int bb = (mt * 128) >> 9;        // batch
  const int t0 = (mt * 128) & 511;       // time tile start
  const int h0 = nt * 128;
  const int tid = threadIdx.x;
  const int wv = tid >> 6, l = tid & 63;
  const int wr = wv >> 1, wc = wv & 1;
  const int sRow = wv * 8 + (l >> 3);
  const int sCol = (l & 7) * 8;
  f32x4 acc[4][4];
  #pragma unroll
  for (int m = 0; m < 4; ++m)
    #pragma unroll
    for (int n = 0; n < 4; ++n) acc[m][n] = f32x4{0.f, 0.f, 0.f, 0.f};

  const int kIters = kw * 8;
  const long aRow0 = (long)(bb * 576 + t0 + woff);
  for (int q = 0; q < kIters; ++q) {
    const int w = q >> 3, dsub = (q & 7) << 6;
    const u16* aB = A + (aRow0 + w) * 512 + dsub + sCol;
    const u16* bB = Bm + (long)w * bWStride + (long)h0 * 512 + dsub + sCol;
    __syncthreads();                      // protect LDS from previous iter readers
    #pragma unroll
    for (int c = 0; c < 4; ++c) {
      gload16(aB + (long)(c * 32 + sRow) * 512, &Alds[c * 2048 + wv * 512]);
      gload16(bB + (long)(c * 32 + sRow) * 512, &Blds[c * 2048 + wv * 512]);
    }
    __syncthreads();
    #pragma unroll
    for (int kk = 0; kk < 2; ++kk) {
      short8 af[4], bf[4];
      #pragma unroll
      for (int m = 0; m < 4; ++m)
        af[m] = *(const short8*)&Alds[(wr * 64 + m * 16 + (l & 15)) * 64 + kk * 32 + (l >> 4) * 8];
      #pragma unroll
      for (int n = 0; n < 4; ++n)
        bf[n] = *(const short8*)&Blds[(wc * 64 + n * 16 + (l & 15)) * 64 + kk * 32 + (l >> 4) * 8];
      #pragma unroll
      for (int m = 0; m < 4; ++m)
        #pragma unroll
        for (int n = 0; n < 4; ++n)
          acc[m][n] = __builtin_amdgcn_mfma_f32_16x16x32_bf16(af[m], bf[n], acc[m][n], 0, 0, 0);
    }
  }
  const int lr = (l >> 4) * 4, lc = l & 15;
  #pragma unroll
  for (int m = 0; m < 4; ++m)
    #pragma unroll
    for (int n = 0; n < 4; ++n)
      #pragma unroll
      for (int r = 0; r < 4; ++r) {
        const int row = mt * 128 + wr * 64 + m * 16 + lr + r;
        const int col = h0 + wc * 64 + n * 16 + lc;
        const float v = acc[m][n][r];
        if (outMode == 0) {
          C[(long)row * 512 + col] = f2bf(tanhf(v));
        } else {
          const int b = row >> 9, t = row & 511;
          C[((long)t * 32 + b) * 1536 + col] = f2bf(v);
        }
      }
}

// ---------------- dza[t][b] = za(b,t,:)·wd2 + (g1-g0) -----------------------
__global__ void k_dza(const u16* __restrict__ za, const float* __restrict__ fskip,
                      const float* __restrict__ ug, float* __restrict__ dza) {
  __shared__ float wd2[512];
  const int t = blockIdx.x, tid = threadIdx.x;
  for (int i = tid; i < 512; i += 256) wd2[i] = fskip[(512 + i) * 2 + 1] - fskip[(512 + i) * 2];
  __syncthreads();
  const int b = tid >> 3, seg = (tid & 7) * 64;
  const u16* row = za + ((long)b * 512 + t) * 512 + seg;
  float pp = 0.f;
  #pragma unroll
  for (int j = 0; j < 8; ++j) {
    short8 v = *(const short8*)&row[j * 8];
    #pragma unroll
    for (int e = 0; e < 8; ++e) pp += bf2f((u16)v[e]) * wd2[seg + j * 8 + e];
  }
  pp += __shfl_xor(pp, 1); pp += __shfl_xor(pp, 2); pp += __shfl_xor(pp, 4);
  if ((tid & 7) == 0) {
    float u0 = ug[((long)t * 32 + b) * 2 + 0], u1 = ug[((long)t * 32 + b) * 2 + 1];
    float g0 = -logf(-logf(u0 + 1e-20f) + 1e-20f);
    float g1 = -logf(-logf(u1 + 1e-20f) + 1e-20f);
    dza[t * 32 + b] = pp + (g1 - g0);
  }
}

// ---------------- persistent recurrence: 8 domains x 8 slices ---------------
// Domain d owns batches 4d..4d+3. Slice s owns h-cols [64s,64s+64); W_rec cols
// {j,512+j,1024+j} register-resident as MFMA B-frags. Per step: exchange h via
// MALL-coherent sc0/sc1 accesses (no cache fences!), relaxed counter signal.
__global__ __launch_bounds__(256, 1) void k_rnn(
    const u16* __restrict__ XM, const float* __restrict__ dza,
    const float* __restrict__ Wrec, const float* __restrict__ gbias,
    const float* __restrict__ fskip, float* hbF, u16* hbB,
    u32* cnt, float* __restrict__ out)
{
  const int bid = blockIdx.x, d = bid & 7, s = bid >> 3;
  const int tid = threadIdx.x, wv = tid >> 6, l = tid & 63;
  __shared__ __align__(16) float hF[2048];
  __shared__ __align__(16) u16   hBl[2048];
  __shared__ float wd[512];
  __shared__ float s1s[4];
  for (int i = tid; i < 512; i += 256) wd[i] = fskip[i * 2 + 1] - fskip[i * 2];

  const int colb = s * 64 + wv * 16 + (l & 15);
  // load W_rec slice into registers as B-frags (bf16)
  short8 wf[3][16];
  #pragma unroll
  for (int g = 0; g < 3; ++g)
    #pragma unroll
    for (int kk = 0; kk < 16; ++kk) {
      short8 tmp;
      #pragma unroll
      for (int e = 0; e < 8; ++e)
        tmp[e] = (short)f2bf(Wrec[(long)(kk * 32 + (l >> 4) * 8 + e) * 1536 + g * 512 + colb]);
      wf[g][kk] = tmp;
    }
  float bi[3], br[3];
  #pragma unroll
  for (int g = 0; g < 3; ++g) {
    bi[g] = gbias[g * 512 + colb];
    br[g] = gbias[1536 + g * 512 + colb];
  }
  const int myb = d * 4;
  u32* myCnt = cnt + d * 64;

  for (int t = 0; t < 512; ++t) {
    const int p = t & 1;
    // prefetch xm (independent of h; L2-warm since no more invalidations)
    u16 xmv[3][4];
    if (l < 16) {
      const u16* xr = XM + ((long)t * 32 + myb) * 1536;
      #pragma unroll
      for (int r = 0; r < 4; ++r)
        #pragma unroll
        for (int g = 0; g < 3; ++g)
          xmv[g][r] = xr[(long)r * 1536 + g * 512 + colb];
    }
    const float dzv = dza[t * 32 + myb + wv];

    if (t > 0) {
      // all threads spin (relaxed: no buffer_inv); each thread self-gates its loads
      while (__hip_atomic_load(myCnt, __ATOMIC_RELAXED, __HIP_MEMORY_SCOPE_AGENT) < (u32)(8 * t))
        __builtin_amdgcn_s_sleep(1);
    }
    // coherent h loads straight from MALL
    const long gb = ((long)p * 32 + myb) * 512 + tid * 8;
    f32x4 x0 = ldg_sc(&hbF[gb]);
    f32x4 x1 = ldg_sc(&hbF[gb + 4]);
    short8 h8 = ldg_sc_h(&hbB[gb]);
    asm volatile("s_waitcnt vmcnt(0)" ::: "memory");
    __builtin_amdgcn_sched_barrier(0);
    *(f32x4*)&hF[tid * 8] = x0;
    *(f32x4*)&hF[tid * 8 + 4] = x1;
    *(short8*)&hBl[tid * 8] = h8;
    __syncthreads();
    // skip-gate logit (h part), wave wv handles batch myb+wv
    float pp = 0.f;
    #pragma unroll
    for (int e = 0; e < 8; ++e) pp += hF[wv * 512 + l * 8 + e] * wd[l * 8 + e];
    #pragma unroll
    for (int o = 1; o < 64; o <<= 1) pp += __shfl_xor(pp, o);
    if (l == 0) s1s[wv] = 1.f / (1.f + __expf(-(pp + dzv)));
    __syncthreads();
    // hm = h @ W_rec slice  (M=16 frag, rows 0..3 = batches, rows 4..15 dups)
    f32x4 acc[3];
    acc[0] = f32x4{0.f,0.f,0.f,0.f}; acc[1] = acc[0]; acc[2] = acc[0];
    const int b4 = l & 3;
    #pragma unroll
    for (int kk = 0; kk < 16; ++kk) {
      short8 a = *(const short8*)&hBl[b4 * 512 + kk * 32 + (l >> 4) * 8];
      acc[0] = __builtin_amdgcn_mfma_f32_16x16x32_bf16(a, wf[0][kk], acc[0], 0, 0, 0);
      acc[1] = __builtin_amdgcn_mfma_f32_16x16x32_bf16(a, wf[1][kk], acc[1], 0, 0, 0);
      acc[2] = __builtin_amdgcn_mfma_f32_16x16x32_bf16(a, wf[2][kk], acc[2], 0, 0, 0);
    }
    // gates + skip blend on lanes 0..15 (C rows 0..3 = batches, reg index = batch)
    float hnv[4];
    if (l < 16) {
      #pragma unroll
      for (int r = 0; r < 4; ++r) {
        const float xz = bf2f(xmv[0][r]) + bi[0];
        const float xr_ = bf2f(xmv[1][r]) + bi[1];
        const float xh = bf2f(xmv[2][r]) + bi[2];
        const float hz = acc[0][r] + br[0];
        const float hr = acc[1][r] + br[1];
        const float hh = acc[2][r] + br[2];
        const float z  = 1.f / (1.f + __expf(-(xz + hz)));
        const float rr = 1.f / (1.f + __expf(-(xr_ + hr)));
        const float hc = tanhf(xh + rr * hh);
        const float hp = hF[r * 512 + colb];
        const float ht = z * hp + (1.f - z) * hc;
        const float s1 = s1s[r];
        const float hn = hp + s1 * (ht - hp);
        hnv[r] = hn;
        const long go = ((long)(p ^ 1) * 32 + myb + r) * 512 + colb;
        stg_sc(&hbF[go], hn);
        stg_sc_h(&hbB[go], f2bf(hn));
      }
    }
    // drain sc1 stores to the MALL, then signal; out-store is off critical path
    asm volatile("s_waitcnt vmcnt(0)" ::: "memory");
    __syncthreads();
    if (tid == 0) __hip_atomic_fetch_add(myCnt, 1u, __ATOMIC_RELAXED, __HIP_MEMORY_SCOPE_AGENT);
    if (l < 16) {
      #pragma unroll
      for (int r = 0; r < 4; ++r)
        out[((long)(myb + r) * 512 + t) * 512 + colb] = hnv[r];
    }
  }
}

// -----------------------------------------------------------------------------
extern "C" void kernel_launch(void* const* d_in, const int* in_sizes, int n_in,
                              void* d_out, int out_size, void* d_ws, size_t ws_size,
                              hipStream_t stream) {
  (void)in_sizes; (void)n_in; (void)out_size; (void)ws_size;
  const float* x        = (const float*)d_in[0];
  const float* f_after  = (const float*)d_in[1];
  const float* f_skip   = (const float*)d_in[2];
  const float* gru_k    = (const float*)d_in[3];
  const float* gru_rec  = (const float*)d_in[4];
  const float* gru_bias = (const float*)d_in[5];
  const float* ug       = (const float*)d_in[6];
  float* out = (float*)d_out;

  char* ws = (char*)d_ws;
  size_t off = 0;
  auto alloc = [&](size_t bytes) { void* p = ws + off; off = (off + bytes + 255) & ~(size_t)255; return p; };
  u16*  xp   = (u16*)alloc(32L * 576 * 512 * 2);
  u16*  fT   = (u16*)alloc(64L * 512 * 512 * 2);
  u16*  gruT = (u16*)alloc(1536L * 512 * 2);
  u16*  za   = (u16*)alloc(32L * 512 * 512 * 2);
  u16*  XM   = (u16*)alloc(512L * 32 * 1536 * 2);
  float* dza = (float*)alloc(512L * 32 * 4);
  float* hbF = (float*)alloc(2L * 32 * 512 * 4);
  u16*  hbB  = (u16*)alloc(2L * 32 * 512 * 2);
  u32*  cnt  = (u32*)alloc(512 * 4);

  k_init<<<dim3(4096), dim3(256), 0, stream>>>(x, xp, hbF, hbB, cnt);
  // f_after [64][512d][512h] -> fT [64][512h][512d]
  k_transpose_cast<<<dim3(8, 8, 64), dim3(256), 0, stream>>>(f_after, fT, 512, 512, 512L * 512, 512L * 512);
  // gru_kernel [512d][1536h] -> gruT [1536h][512d]
  k_transpose_cast<<<dim3(24, 8, 1), dim3(256), 0, stream>>>(gru_k, gruT, 512, 1536, 0L, 0L);
  // conv: za = tanh(conv1d(x, f_after))
  k_gemm<<<dim3(512), dim3(256), 0, stream>>>(xp, fT, za, 4, 64, 0, 512L * 512, 0);
  // XM = x @ gru_kernel  (stored [t][b][1536])
  k_gemm<<<dim3(1536), dim3(256), 0, stream>>>(xp, gruT, XM, 12, 1, 31, 0L, 1);
  // dza = za·wd2 + gumbel diff
  k_dza<<<dim3(512), dim3(256), 0, stream>>>(za, f_skip, ug, dza);
  // sequential recurrence
  k_rnn<<<dim3(64), dim3(256), 0, stream>>>(XM, dza, gru_rec, gru_bias, f_skip, hbF, hbB, cnt, out);
}

// Round 4
// 2206.597 us; speedup vs baseline: 3.5106x; 1.1317x over previous
//
#include <hip/hip_runtime.h>
#include <stdint.h>

typedef unsigned short u16;
typedef unsigned int   u32;
typedef __attribute__((ext_vector_type(8))) short short8;
typedef __attribute__((ext_vector_type(4))) float f32x4;
typedef __attribute__((ext_vector_type(4))) u32   u32x4;

#define AS1 __attribute__((address_space(1)))
#define AS3 __attribute__((address_space(3)))

#define SENT 0x7FC0u   // bf16 NaN sentinel: unreachable by f2bf of finite |h|<1.05

__device__ __forceinline__ float bf2f(u16 u) {
  union { u32 i; float f; } v; v.i = ((u32)u) << 16; return v.f;
}
__device__ __forceinline__ u16 f2bf(float f) {
  union { float f; u32 i; } v; v.f = f;
  u32 i = v.i;
  i += 0x7FFFu + ((i >> 16) & 1u);   // round-to-nearest-even
  return (u16)(i >> 16);
}

__device__ __forceinline__ void gload16(const u16* src, u16* ldsDst) {
  __builtin_amdgcn_global_load_lds((const AS1 u32*)src, (AS3 u32*)ldsDst, 16, 0, 0);
}

// ---- MALL-coherent (cache-bypassing) h exchange -----------------------------
// NOTE: the s_waitcnt MUST live inside the asm block — LLVM's waitcnt pass
// does not model VMEM ops hidden in inline asm (round-3 hang root cause).
__device__ __forceinline__ short8 ldg_sc_h_wait(const u16* p) {
  short8 r;
  asm volatile("global_load_dwordx4 %0, %1, off sc0 sc1\n\t"
               "s_waitcnt vmcnt(0)"
               : "=v"(r) : "v"(p) : "memory");
  return r;
}
__device__ __forceinline__ void stg_sc_h(u16* p, u16 v) {
  asm volatile("global_store_short %0, %1, off sc0 sc1" :: "v"(p), "v"((u32)v) : "memory");
}

// ---------------- init: pad+cast x ------------------------------------------
__global__ void k_init(const float* __restrict__ x, u16* __restrict__ xp) {
  const long NXP = 32L * 576 * 512;
  long i0 = (long)blockIdx.x * 256 + threadIdx.x;
  for (long i = i0; i < NXP; i += (long)gridDim.x * 256) {
    long b = i / (576 * 512);
    int rem = (int)(i - b * (576 * 512));
    int rr = rem >> 9, dd = rem & 511;
    int t = rr - 31;                       // SAME pad: 31 left, 33 right
    float v = (t >= 0 && t < 512) ? x[(b * 512 + t) * 512 + dd] : 0.f;
    xp[i] = f2bf(v);
  }
}

// ---------------- sentinel fill of hstep (16.77 MB) --------------------------
__global__ void k_sent(u32* __restrict__ hs) {
  const u32x4 s = u32x4{(SENT << 16) | SENT, (SENT << 16) | SENT,
                        (SENT << 16) | SENT, (SENT << 16) | SENT};
  *(u32x4*)&hs[((long)blockIdx.x * 256 + threadIdx.x) * 4] = s;
}

// ---------------- transpose + cast fp32 -> bf16 ------------------------------
__global__ void k_transpose_cast(const float* __restrict__ in, u16* __restrict__ out,
                                 int rows, int cols, long inWStride, long outWStride) {
  __shared__ float tile[64][65];
  const int w = blockIdx.z;
  const float* ip = in + (long)w * inWStride;
  u16* op = out + (long)w * outWStride;
  const int r0 = blockIdx.y * 64, c0 = blockIdx.x * 64;
  const int tr = threadIdx.x >> 6, tc = threadIdx.x & 63;
  #pragma unroll
  for (int p = 0; p < 16; ++p) {
    int rr = p * 4 + tr;
    tile[rr][tc] = ip[(long)(r0 + rr) * cols + c0 + tc];
  }
  __syncthreads();
  #pragma unroll
  for (int p = 0; p < 16; ++p) {
    int rr = p * 4 + tr;
    op[(long)(c0 + rr) * rows + r0 + tc] = f2bf(tile[tc][rr]);
  }
}

// ---------------- tiled MFMA GEMM (conv via w-shift, and XM) -----------------
__global__ __launch_bounds__(256) void k_gemm(
    const u16* __restrict__ A, const u16* __restrict__ Bm, u16* __restrict__ C,
    int nTiles, int kw, int woff, long bWStride, int outMode)
{
  __shared__ __align__(16) u16 Alds[128 * 64];
  __shared__ __align__(16) u16 Blds[128 * 64];
  const int bid = blockIdx.x;
  const int mt = bid / nTiles, nt = bid - mt * nTiles;
  const int bb = (mt * 128) >> 9;
  const int t0 = (mt * 128) & 511;
  const int h0 = nt * 128;
  const int tid = threadIdx.x;
  const int wv = tid >> 6, l = tid & 63;
  const int wr = wv >> 1, wc = wv & 1;
  const int sRow = wv * 8 + (l >> 3);
  const int sCol = (l & 7) * 8;
  f32x4 acc[4][4];
  #pragma unroll
  for (int m = 0; m < 4; ++m)
    #pragma unroll
    for (int n = 0; n < 4; ++n) acc[m][n] = f32x4{0.f, 0.f, 0.f, 0.f};

  const int kIters = kw * 8;
  const long aRow0 = (long)(bb * 576 + t0 + woff);
  for (int q = 0; q < kIters; ++q) {
    const int w = q >> 3, dsub = (q & 7) << 6;
    const u16* aB = A + (aRow0 + w) * 512 + dsub + sCol;
    const u16* bB = Bm + (long)w * bWStride + (long)h0 * 512 + dsub + sCol;
    __syncthreads();
    #pragma unroll
    for (int c = 0; c < 4; ++c) {
      gload16(aB + (long)(c * 32 + sRow) * 512, &Alds[c * 2048 + wv * 512]);
      gload16(bB + (long)(c * 32 + sRow) * 512, &Blds[c * 2048 + wv * 512]);
    }
    __syncthreads();
    #pragma unroll
    for (int kk = 0; kk < 2; ++kk) {
      short8 af[4], bf[4];
      #pragma unroll
      for (int m = 0; m < 4; ++m)
        af[m] = *(const short8*)&Alds[(wr * 64 + m * 16 + (l & 15)) * 64 + kk * 32 + (l >> 4) * 8];
      #pragma unroll
      for (int n = 0; n < 4; ++n)
        bf[n] = *(const short8*)&Blds[(wc * 64 + n * 16 + (l & 15)) * 64 + kk * 32 + (l >> 4) * 8];
      #pragma unroll
      for (int m = 0; m < 4; ++m)
        #pragma unroll
        for (int n = 0; n < 4; ++n)
          acc[m][n] = __builtin_amdgcn_mfma_f32_16x16x32_bf16(af[m], bf[n], acc[m][n], 0, 0, 0);
    }
  }
  const int lr = (l >> 4) * 4, lc = l & 15;
  #pragma unroll
  for (int m = 0; m < 4; ++m)
    #pragma unroll
    for (int n = 0; n < 4; ++n)
      #pragma unroll
      for (int r = 0; r < 4; ++r) {
        const int row = mt * 128 + wr * 64 + m * 16 + lr + r;
        const int col = h0 + wc * 64 + n * 16 + lc;
        const float v = acc[m][n][r];
        if (outMode == 0) {
          C[(long)row * 512 + col] = f2bf(tanhf(v));
        } else {
          const int b = row >> 9, t = row & 511;
          C[((long)t * 32 + b) * 1536 + col] = f2bf(v);
        }
      }
}

// ---------------- dza[t][b] = za(b,t,:)·wd2 + (g1-g0) -----------------------
__global__ void k_dza(const u16* __restrict__ za, const float* __restrict__ fskip,
                      const float* __restrict__ ug, float* __restrict__ dza) {
  __shared__ float wd2[512];
  const int t = blockIdx.x, tid = threadIdx.x;
  for (int i = tid; i < 512; i += 256) wd2[i] = fskip[(512 + i) * 2 + 1] - fskip[(512 + i) * 2];
  __syncthreads();
  const int b = tid >> 3, seg = (tid & 7) * 64;
  const u16* row = za + ((long)b * 512 + t) * 512 + seg;
  float pp = 0.f;
  #pragma unroll
  for (int j = 0; j < 8; ++j) {
    short8 v = *(const short8*)&row[j * 8];
    #pragma unroll
    for (int e = 0; e < 8; ++e) pp += bf2f((u16)v[e]) * wd2[seg + j * 8 + e];
  }
  pp += __shfl_xor(pp, 1); pp += __shfl_xor(pp, 2); pp += __shfl_xor(pp, 4);
  if ((tid & 7) == 0) {
    float u0 = ug[((long)t * 32 + b) * 2 + 0], u1 = ug[((long)t * 32 + b) * 2 + 1];
    float g0 = -logf(-logf(u0 + 1e-20f) + 1e-20f);
    float g1 = -logf(-logf(u1 + 1e-20f) + 1e-20f);
    dza[t * 32 + b] = pp + (g1 - g0);
  }
}

// ---------------- persistent recurrence: 8 domains x 8 slices ---------------
// Data-is-flag exchange: per-step bf16 h buffers pre-filled with NaN sentinel.
// Producers fire sc0/sc1 stores (no signal); consumers poll their own 16B of
// hstep[t-1] until sentinel-free (each poll load waits vmcnt(0) INSIDE asm).
__global__ __launch_bounds__(256, 1) void k_rnn(
    const u16* __restrict__ XM, const float* __restrict__ dza,
    const float* __restrict__ Wrec, const float* __restrict__ gbias,
    const float* __restrict__ fskip, u16* hstep, float* __restrict__ out)
{
  const int bid = blockIdx.x, d = bid & 7, s = bid >> 3;
  const int tid = threadIdx.x, wv = tid >> 6, l = tid & 63;
  __shared__ __align__(16) u16 hBl[2][2048];
  __shared__ float s1s[2][4];

  // skip-gate h-weights for this lane's 8 columns (col = l*8+e)
  float wdv[8];
  #pragma unroll
  for (int e = 0; e < 8; ++e)
    wdv[e] = fskip[(l * 8 + e) * 2 + 1] - fskip[(l * 8 + e) * 2];

  const int colb = s * 64 + wv * 16 + (l & 15);
  // W_rec slice -> register B-frags (bf16)
  short8 wf[3][16];
  #pragma unroll
  for (int g = 0; g < 3; ++g)
    #pragma unroll
    for (int kk = 0; kk < 16; ++kk) {
      short8 tmp;
      #pragma unroll
      for (int e = 0; e < 8; ++e)
        tmp[e] = (short)f2bf(Wrec[(long)(kk * 32 + (l >> 4) * 8 + e) * 1536 + g * 512 + colb]);
      wf[g][kk] = tmp;
    }
  float bi[3], br[3];
  #pragma unroll
  for (int g = 0; g < 3; ++g) {
    bi[g] = gbias[g * 512 + colb];
    br[g] = gbias[1536 + g * 512 + colb];
  }
  const int myb = d * 4;
  float hp[4] = {0.f, 0.f, 0.f, 0.f};   // own-column fp32 h state (l<16 lanes)

  for (int t = 0; t < 512; ++t) {
    const int p = t & 1;
    // prefetch xm + dza (independent of h; land during the poll)
    u16 xmv[3][4];
    if (l < 16) {
      const u16* xr = XM + ((long)t * 32 + myb) * 1536;
      #pragma unroll
      for (int r = 0; r < 4; ++r)
        #pragma unroll
        for (int g = 0; g < 3; ++g)
          xmv[g][r] = xr[(long)r * 1536 + g * 512 + colb];
    }
    const float dzv = dza[t * 32 + myb + wv];

    // ---- acquire h_{t-1}: poll own 16B until sentinel-free ----
    short8 h8;
    if (t > 0) {
      const u16* ph = hstep + ((long)(t - 1) * 32 + myb + wv) * 512 + l * 8;
      h8 = ldg_sc_h_wait(ph);
      bool bad = true;
      while (bad) {
        bad = false;
        #pragma unroll
        for (int e = 0; e < 8; ++e) bad |= ((u16)h8[e] == SENT);
        if (bad) h8 = ldg_sc_h_wait(ph);
      }
    } else {
      #pragma unroll
      for (int e = 0; e < 8; ++e) h8[e] = 0;
    }

    // skip-gate logit (h part) from bf16 h; wave wv = batch myb+wv
    float pp = 0.f;
    #pragma unroll
    for (int e = 0; e < 8; ++e) pp += bf2f((u16)h8[e]) * wdv[e];
    #pragma unroll
    for (int o = 1; o < 64; o <<= 1) pp += __shfl_xor(pp, o);
    if (l == 0) s1s[p][wv] = 1.f / (1.f + __expf(-(pp + dzv)));
    *(short8*)&hBl[p][tid * 8] = h8;
    __syncthreads();

    // hm = h @ W_rec slice  (rows 0..3 = batches)
    f32x4 acc[3];
    acc[0] = f32x4{0.f, 0.f, 0.f, 0.f}; acc[1] = acc[0]; acc[2] = acc[0];
    const int b4 = l & 3;
    #pragma unroll
    for (int kk = 0; kk < 16; ++kk) {
      short8 a = *(const short8*)&hBl[p][b4 * 512 + kk * 32 + (l >> 4) * 8];
      acc[0] = __builtin_amdgcn_mfma_f32_16x16x32_bf16(a, wf[0][kk], acc[0], 0, 0, 0);
      acc[1] = __builtin_amdgcn_mfma_f32_16x16x32_bf16(a, wf[1][kk], acc[1], 0, 0, 0);
      acc[2] = __builtin_amdgcn_mfma_f32_16x16x32_bf16(a, wf[2][kk], acc[2], 0, 0, 0);
    }
    // gates + skip blend; publish h_t immediately (data IS the flag)
    if (l < 16) {
      #pragma unroll
      for (int r = 0; r < 4; ++r) {
        const float xz = bf2f(xmv[0][r]) + bi[0];
        const float xr_ = bf2f(xmv[1][r]) + bi[1];
        const float xh = bf2f(xmv[2][r]) + bi[2];
        const float hz = acc[0][r] + br[0];
        const float hr = acc[1][r] + br[1];
        const float hh = acc[2][r] + br[2];
        const float z  = 1.f / (1.f + __expf(-(xz + hz)));
        const float rr = 1.f / (1.f + __expf(-(xr_ + hr)));
        const float hc = tanhf(xh + rr * hh);
        const float ht = z * hp[r] + (1.f - z) * hc;
        const float s1 = s1s[p][r];
        const float hn = hp[r] + s1 * (ht - hp[r]);
        stg_sc_h(&hstep[((long)t * 32 + myb + r) * 512 + colb], f2bf(hn));
        hp[r] = hn;
      }
      #pragma unroll
      for (int r = 0; r < 4; ++r)
        out[((long)(myb + r) * 512 + t) * 512 + colb] = hp[r];
    }
    // drain own stores so next-step self-poll sees them
    asm volatile("s_waitcnt vmcnt(0)" ::: "memory");
  }
}

// -----------------------------------------------------------------------------
extern "C" void kernel_launch(void* const* d_in, const int* in_sizes, int n_in,
                              void* d_out, int out_size, void* d_ws, size_t ws_size,
                              hipStream_t stream) {
  (void)in_sizes; (void)n_in; (void)out_size; (void)ws_size;
  const float* x        = (const float*)d_in[0];
  const float* f_after  = (const float*)d_in[1];
  const float* f_skip   = (const float*)d_in[2];
  const float* gru_k    = (const float*)d_in[3];
  const float* gru_rec  = (const float*)d_in[4];
  const float* gru_bias = (const float*)d_in[5];
  const float* ug       = (const float*)d_in[6];
  float* out = (float*)d_out;

  char* ws = (char*)d_ws;
  size_t off = 0;
  auto alloc = [&](size_t bytes) { void* p = ws + off; off = (off + bytes + 255) & ~(size_t)255; return p; };
  u16*  xp    = (u16*)alloc(32L * 576 * 512 * 2);
  u16*  fT    = (u16*)alloc(64L * 512 * 512 * 2);
  u16*  gruT  = (u16*)alloc(1536L * 512 * 2);
  u16*  za    = (u16*)alloc(32L * 512 * 512 * 2);   // reused as hstep after k_dza
  u16*  XM    = (u16*)alloc(512L * 32 * 1536 * 2);
  float* dza  = (float*)alloc(512L * 32 * 4);
  u16*  hstep = za;                                  // [512][32][512] bf16

  k_init<<<dim3(4096), dim3(256), 0, stream>>>(x, xp);
  k_transpose_cast<<<dim3(8, 8, 64), dim3(256), 0, stream>>>(f_after, fT, 512, 512, 512L * 512, 512L * 512);
  k_transpose_cast<<<dim3(24, 8, 1), dim3(256), 0, stream>>>(gru_k, gruT, 512, 1536, 0L, 0L);
  k_gemm<<<dim3(512), dim3(256), 0, stream>>>(xp, fT, za, 4, 64, 0, 512L * 512, 0);
  k_gemm<<<dim3(1536), dim3(256), 0, stream>>>(xp, gruT, XM, 12, 1, 31, 0L, 1);
  k_dza<<<dim3(512), dim3(256), 0, stream>>>(za, f_skip, ug, dza);
  k_sent<<<dim3(4096), dim3(256), 0, stream>>>((u32*)hstep);
  k_rnn<<<dim3(64), dim3(256), 0, stream>>>(XM, dza, gru_rec, gru_bias, f_skip, hstep, out);
}